// Round 3
// baseline (3869.385 us; speedup 1.0000x reference)
//
#include <hip/hip_runtime.h>
#include <hip/hip_bf16.h>
#include <math.h>

// FNO3D on MI355X. Inputs fp32, internal fp32, output fp32.
// B=4, C=24, 64^3 grid, modes 12^3, 4 layers.

static constexpr int BN = 4;
static constexpr int CW = 24;
static constexpr int ZD = 64;
static constexpr size_t NPTS = 64ull * 64 * 64;      // 262144
static constexpr int KM = 12;
static constexpr int KK2 = 144;
static constexpr int M3 = 1728;
static constexpr int NLAYERS = 4;

// Workspace layout (floats). Total ~62.2M floats = 249 MB.
static constexpr size_t OFF_H     = 0;                                     // h  [B][C][Z][Y][X]
static constexpr size_t OFF_PRE   = OFF_H   + (size_t)BN * CW * NPTS;      // pre (same shape)
static constexpr size_t OFF_A1    = OFF_PRE + (size_t)BN * CW * NPTS;      // A1 [b][c][z][kx][y] cplx  (shared with B2 [b][o][z][y][kx])
static constexpr size_t OFF_A2    = OFF_A1  + (size_t)BN * CW * ZD * KM * ZD * 2; // A2 [b][c][ky*12+kx][z] cplx (shared with B1 [b][o][z][kk])
static constexpr size_t OFF_HF    = OFF_A2  + (size_t)BN * CW * KK2 * ZD * 2;     // Hf [b][c][mode] cplx
static constexpr size_t OFF_OUT   = OFF_HF  + (size_t)BN * CW * M3 * 2;           // Out [b][o][mode] cplx
static constexpr size_t OFF_AX    = OFF_OUT + (size_t)BN * CW * M3 * 2;           // axis tables 3*24*64
static constexpr size_t OFF_STATS = OFF_AX  + 3 * CW * 64;                        // [layer][b][2]
static constexpr size_t OFF_NORM  = OFF_STATS + NLAYERS * BN * 2;                 // [layer][b][2]

__device__ __forceinline__ float gelu_exact(float y) {
  return 0.5f * y * (1.f + erff(y * 0.70710678118654752f));
}

// ---------------- axis tables for the lift (posenc is separable) -------------
__global__ void k_axis(const float* __restrict__ lw, float* __restrict__ ws) {
  int t = blockIdx.x * blockDim.x + threadIdx.x;
  if (t >= 3 * CW * 64) return;
  int v = t & 63;
  int o = (t >> 6) % CW;
  int axis = t / (64 * CW);
  float val = -1.f + 2.f * (float)v / 63.f;
  float acc = lw[o * 54 + 3 + axis] * val;   // linear coordinate channel
  for (int k = 1; k <= 8; k++) {
    float s, c;
    sincosf((float)k * 3.14159265358979323846f * val, &s, &c);
    int base = 6 + 6 * (k - 1) + 2 * axis;
    acc += lw[o * 54 + base] * s + lw[o * 54 + base + 1] * c;
  }
  ws[OFF_AX + (size_t)axis * CW * 64 + o * 64 + v] = acc;
}

// ---------------- lift: h = W*x + a_z + a_y + a_x + b ------------------------
__global__ __launch_bounds__(64) void k_lift(const float* __restrict__ xin,
                                             const float* __restrict__ lw,
                                             const float* __restrict__ lb,
                                             float* __restrict__ ws) {
  int bid = blockIdx.x;                  // b*4096 + z*64 + y
  int b = bid >> 12, z = (bid >> 6) & 63, y = bid & 63;
  int tx = threadIdx.x;
  size_t zyx = (size_t)z * 4096 + y * 64 + tx;
  float x0 = xin[(size_t)(b * 3 + 0) * NPTS + zyx];
  float x1 = xin[(size_t)(b * 3 + 1) * NPTS + zyx];
  float x2 = xin[(size_t)(b * 3 + 2) * NPTS + zyx];
  const float* az = ws + OFF_AX;
  const float* ay = az + CW * 64;
  const float* axt = ay + CW * 64;
  float* h = ws + OFF_H;
  for (int o = 0; o < CW; o++) {
    float acc = lb[o] + lw[o * 54 + 0] * x0 + lw[o * 54 + 1] * x1 +
                lw[o * 54 + 2] * x2 + az[o * 64 + z] + ay[o * 64 + y] + axt[o * 64 + tx];
    h[(size_t)(b * CW + o) * NPTS + zyx] = acc;
  }
}

// ---------------- forward DFT along x (real -> 12 modes) ---------------------
__global__ void k_dftx(const float* __restrict__ hsrc, float* __restrict__ A1) {
  __shared__ float pl[64][65];
  __shared__ float twc[64], tws[64];
  int bid = blockIdx.x;                  // bc*64 + z
  const float* src = hsrc + (size_t)bid * 4096;  // h[bc][z][:][:] since bid = bc*64+z
  int t = threadIdx.x;
  for (int i = t; i < 4096; i += 256) pl[i >> 6][i & 63] = src[i];
  if (t < 64) { float s, c; sincosf(6.283185307179586f * t / 64.f, &s, &c); twc[t] = c; tws[t] = s; }
  __syncthreads();
  float2* dst = (float2*)A1 + (size_t)bid * KM * 64;
  for (int i = t; i < KM * 64; i += 256) {
    int y = i & 63, kx = i >> 6;
    float re = 0.f, im = 0.f;
    for (int xx = 0; xx < 64; xx++) {
      float v = pl[y][xx];
      int tt = (kx * xx) & 63;
      re += v * twc[tt];
      im -= v * tws[tt];
    }
    dst[i] = make_float2(re, im);        // i = kx*64+y -> layout [kx][y]
  }
}

// ---------------- forward DFT along y ----------------------------------------
__global__ void k_dfty(const float* __restrict__ A1, float* __restrict__ A2) {
  __shared__ float lre[12][65], lim[12][65];
  __shared__ float twc[64], tws[64];
  int bid = blockIdx.x;                  // bc*64 + z
  int z = bid & 63, bc = bid >> 6;
  const float2* src = (const float2*)A1 + (size_t)bid * KM * 64;
  int t = threadIdx.x;
  for (int i = t; i < 768; i += 256) { float2 v = src[i]; lre[i >> 6][i & 63] = v.x; lim[i >> 6][i & 63] = v.y; }
  if (t < 64) { float s, c; sincosf(6.283185307179586f * t / 64.f, &s, &c); twc[t] = c; tws[t] = s; }
  __syncthreads();
  if (t < KK2) {
    int ky = t / 12, kx = t % 12;
    float re = 0.f, im = 0.f;
    for (int y = 0; y < 64; y++) {
      float ar = lre[kx][y], ai = lim[kx][y];
      int tt = (ky * y) & 63;
      float c = twc[tt], s = tws[tt];
      re += ar * c + ai * s;             // * e^{-i t}
      im += ai * c - ar * s;
    }
    ((float2*)A2)[((size_t)bc * KK2 + t) * 64 + z] = make_float2(re, im);
  }
}

// ---------------- forward DFT along z ----------------------------------------
__global__ void k_dftz(const float* __restrict__ A2, float* __restrict__ Hf) {
  __shared__ float lre[12][65], lim[12][65];
  __shared__ float twc[64], tws[64];
  int bid = blockIdx.x;                  // bc*12 + ky
  int ky = bid % 12, bc = bid / 12;
  const float2* src = (const float2*)A2 + ((size_t)bc * KK2 + ky * 12) * 64;  // [kx][z]
  int t = threadIdx.x;
  for (int i = t; i < 768; i += 256) { float2 v = src[i]; lre[i >> 6][i & 63] = v.x; lim[i >> 6][i & 63] = v.y; }
  if (t < 64) { float s, c; sincosf(6.283185307179586f * t / 64.f, &s, &c); twc[t] = c; tws[t] = s; }
  __syncthreads();
  if (t < KK2) {
    int kz = t / 12, kx = t % 12;
    float re = 0.f, im = 0.f;
    for (int zz = 0; zz < 64; zz++) {
      float ar = lre[kx][zz], ai = lim[kx][zz];
      int tt = (kz * zz) & 63;
      float c = twc[tt], s = tws[tt];
      re += ar * c + ai * s;
      im += ai * c - ar * s;
    }
    ((float2*)Hf)[(size_t)bc * M3 + kz * KK2 + ky * 12 + kx] = make_float2(re, im);
  }
}

// ---------------- mode mix: Out[b,o,m] = sum_c Hf[b,c,m]*W[c,o,m] ------------
__global__ void k_mix(const float* __restrict__ Hf, const float* __restrict__ specw,
                      float* __restrict__ Outb, int layer) {
  __shared__ float hre[24][64], him[24][64];
  int bid = blockIdx.x;                  // b*27 + chunk
  int chunk = bid % 27, b = bid / 27;
  int m0 = chunk * 64;
  int t = threadIdx.x;
  const float2* hf = (const float2*)Hf + (size_t)b * CW * M3;
  for (int i = t; i < 24 * 64; i += 256) {
    int c = i >> 6, m = i & 63;
    float2 v = hf[(size_t)c * M3 + m0 + m];
    hre[c][m] = v.x; him[c][m] = v.y;
  }
  __syncthreads();
  const float2* W2 = (const float2*)specw + (size_t)layer * 576 * M3;
  float2* outp = (float2*)Outb + (size_t)b * CW * M3;
  for (int p = t; p < 24 * 64; p += 256) {
    int o = p >> 6, m = p & 63;
    int mg = m0 + m;
    float re = 0.f, im = 0.f;
    for (int c = 0; c < 24; c++) {
      float2 w = W2[(size_t)(c * 24 + o) * M3 + mg];
      float wr = w.x, wi = w.y;
      float ar = hre[c][m], ai = him[c][m];
      re += ar * wr - ai * wi;
      im += ar * wi + ai * wr;
    }
    int kx = mg % 12;
    float sc = (kx == 0 ? 1.f : 2.f) * (1.f / 262144.f);  // irfftn scale + rfft doubling
    outp[(size_t)o * M3 + mg] = make_float2(re * sc, im * sc);
  }
}

// ---------------- inverse DFT along z ----------------------------------------
__global__ void k_invz(const float* __restrict__ Outb, float* __restrict__ B1) {
  __shared__ float lre[1728], lim[1728];
  __shared__ float twc[64], tws[64];
  int bo = blockIdx.x;
  const float2* src = (const float2*)Outb + (size_t)bo * M3;
  int t = threadIdx.x;
  for (int i = t; i < 1728; i += 256) { float2 v = src[i]; lre[i] = v.x; lim[i] = v.y; }
  if (t < 64) { float s, c; sincosf(6.283185307179586f * t / 64.f, &s, &c); twc[t] = c; tws[t] = s; }
  __syncthreads();
  float2* dst = (float2*)B1 + (size_t)bo * 64 * KK2;
  for (int p = t; p < 64 * KK2; p += 256) {
    int z = p / KK2, kk = p % KK2;
    float re = 0.f, im = 0.f;
    for (int kz = 0; kz < 12; kz++) {
      float ar = lre[kz * KK2 + kk], ai = lim[kz * KK2 + kk];
      int tt = (kz * z) & 63;
      float c = twc[tt], s = tws[tt];
      re += ar * c - ai * s;             // * e^{+i t}
      im += ar * s + ai * c;
    }
    dst[p] = make_float2(re, im);
  }
}

// ---------------- inverse DFT along y ----------------------------------------
__global__ void k_invy(const float* __restrict__ B1, float* __restrict__ B2) {
  __shared__ float lre[144], lim[144];
  __shared__ float twc[64], tws[64];
  int bid = blockIdx.x;                  // bo*64 + z
  const float2* src = (const float2*)B1 + (size_t)bid * KK2;
  int t = threadIdx.x;
  if (t < 144) { float2 v = src[t]; lre[t] = v.x; lim[t] = v.y; }
  if (t < 64) { float s, c; sincosf(6.283185307179586f * t / 64.f, &s, &c); twc[t] = c; tws[t] = s; }
  __syncthreads();
  float2* dst = (float2*)B2 + (size_t)bid * 64 * KM;
  for (int p = t; p < 64 * KM; p += 256) {
    int y = p / KM, kx = p % KM;
    float re = 0.f, im = 0.f;
    for (int ky = 0; ky < 12; ky++) {
      float ar = lre[ky * 12 + kx], ai = lim[ky * 12 + kx];
      int tt = (ky * y) & 63;
      float c = twc[tt], s = tws[tt];
      re += ar * c - ai * s;
      im += ar * s + ai * c;
    }
    dst[p] = make_float2(re, im);        // p = y*12+kx -> layout [y][kx]
  }
}

// ------- fused: inverse-x + ws conv + depthwise + gelu + residual + GN sums ---
__global__ __launch_bounds__(64) void k_layer(const float* __restrict__ hsrc,
                                              const float* __restrict__ B2f,
                                              const float* __restrict__ wsw,
                                              const float* __restrict__ wsb,
                                              const float* __restrict__ locw,
                                              const float* __restrict__ locb,
                                              const float* __restrict__ gammas,
                                              float* __restrict__ pre,
                                              float* __restrict__ stats, int layer) {
  __shared__ float s_ws[576];
  __shared__ float s_loc[648];
  __shared__ float s_sp[576];            // [o][kx][2]
  __shared__ float s_wsb[24], s_locb[24];
  __shared__ float twc[64], tws[64];
  int bid = blockIdx.x;                  // b*4096 + z*64 + y
  int b = bid >> 12, z = (bid >> 6) & 63, y = bid & 63;
  int tx = threadIdx.x;

  for (int i = tx; i < 576; i += 64) s_ws[i] = wsw[layer * 576 + i];
  for (int i = tx; i < 648; i += 64) s_loc[i] = locw[layer * 648 + i];
  const float2* b2 = (const float2*)B2f;
  for (int i = tx; i < 288; i += 64) {
    int o = i / 12, kx = i % 12;
    float2 v = b2[(((size_t)(b * CW + o) * 64 + z) * 64 + y) * KM + kx];
    s_sp[i * 2] = v.x; s_sp[i * 2 + 1] = v.y;
  }
  if (tx < 24) { s_wsb[tx] = wsb[layer * 24 + tx]; s_locb[tx] = locb[layer * 24 + tx]; }
  { float s, c; sincosf(6.283185307179586f * tx / 64.f, &s, &c); twc[tx] = c; tws[tx] = s; }
  __syncthreads();

  float gamma = gammas[layer];
  size_t base_b = (size_t)b * CW * NPTS;
  size_t zyx = (size_t)z * 4096 + y * 64 + tx;
  float hreg[24];
  for (int c = 0; c < 24; c++) hreg[c] = hsrc[base_b + (size_t)c * NPTS + zyx];

  float lsum = 0.f, lsq = 0.f;
  for (int o = 0; o < 24; o++) {
    // spectral inverse along x
    float sp = 0.f;
#pragma unroll
    for (int kx = 0; kx < 12; kx++) {
      int tt = (kx * tx) & 63;
      sp += s_sp[(o * 12 + kx) * 2] * twc[tt] - s_sp[(o * 12 + kx) * 2 + 1] * tws[tt];
    }
    // pointwise 24x24
    float wv = 0.f;
#pragma unroll
    for (int c = 0; c < 24; c++) wv += s_ws[o * 24 + c] * hreg[c];
    // depthwise 3x3x3 (cross-correlation, SAME zero padding)
    float dv = 0.f;
    const float* wl = s_loc + o * 27;
    for (int dz = -1; dz <= 1; dz++) {
      int z2 = z + dz;
      bool zok = (unsigned)z2 < 64u;
      for (int dy = -1; dy <= 1; dy++) {
        int y2 = y + dy;
        bool ok = zok && ((unsigned)y2 < 64u);
        float v = 0.f;
        if (dz == 0 && dy == 0) v = hreg[o];
        else if (ok) v = hsrc[base_b + (size_t)o * NPTS + (size_t)z2 * 4096 + y2 * 64 + tx];
        float vm = __shfl_up(v, 1);  if (tx == 0)  vm = 0.f;
        float vp = __shfl_down(v, 1); if (tx == 63) vp = 0.f;
        int wb = (dz + 1) * 9 + (dy + 1) * 3;
        dv += vm * wl[wb] + v * wl[wb + 1] + vp * wl[wb + 2];
      }
    }
    float yv = sp + wv + s_wsb[o] + dv + s_locb[o];
    float pv = hreg[o] + gamma * gelu_exact(yv);
    pre[base_b + (size_t)o * NPTS + zyx] = pv;
    lsum += pv; lsq += pv * pv;
  }
  for (int off = 32; off; off >>= 1) { lsum += __shfl_down(lsum, off); lsq += __shfl_down(lsq, off); }
  if (tx == 0) {
    atomicAdd(&stats[(layer * BN + b) * 2], lsum);
    atomicAdd(&stats[(layer * BN + b) * 2 + 1], lsq);
  }
}

// ---------------- groupnorm finalize -----------------------------------------
__global__ void k_gnstat(const float* __restrict__ stats, float* __restrict__ norm, int layer) {
  int b = threadIdx.x;
  if (b >= BN) return;
  float s1 = stats[(layer * BN + b) * 2];
  float s2 = stats[(layer * BN + b) * 2 + 1];
  float n = (float)(CW * NPTS);
  float mean = s1 / n;
  float var = s2 / n - mean * mean;
  norm[(layer * BN + b) * 2] = mean;
  norm[(layer * BN + b) * 2 + 1] = rsqrtf(var + 1e-5f);
}

// ---------------- groupnorm apply: h = (pre-mean)*rstd*g + b -----------------
__global__ void k_gnapply(const float* __restrict__ pre, float* __restrict__ h,
                          const float* __restrict__ norm,
                          const float* __restrict__ gnw,
                          const float* __restrict__ gnb, int layer) {
  size_t total4 = (size_t)BN * CW * NPTS / 4;
  size_t stride = (size_t)gridDim.x * blockDim.x;
  for (size_t i4 = (size_t)blockIdx.x * blockDim.x + threadIdx.x; i4 < total4; i4 += stride) {
    size_t e = i4 * 4;
    int bc = (int)(e / NPTS);
    int b = bc / CW, c = bc % CW;
    float mean = norm[(layer * BN + b) * 2];
    float rstd = norm[(layer * BN + b) * 2 + 1];
    float gw = gnw[layer * 24 + c] * rstd;
    float gb = gnb[layer * 24 + c];
    float4 v = ((const float4*)pre)[i4];
    v.x = (v.x - mean) * gw + gb;
    v.y = (v.y - mean) * gw + gb;
    v.z = (v.z - mean) * gw + gb;
    v.w = (v.w - mean) * gw + gb;
    ((float4*)h)[i4] = v;
  }
}

// ---------------- projection head --------------------------------------------
__global__ __launch_bounds__(64) void k_proj(const float* __restrict__ h,
                                             const float* __restrict__ p1w,
                                             const float* __restrict__ p1b,
                                             const float* __restrict__ p2w,
                                             const float* __restrict__ p2b,
                                             float* __restrict__ out) {
  __shared__ float s_w[576], s_b[24], s_w2[24];
  int bid = blockIdx.x;
  int b = bid >> 12, z = (bid >> 6) & 63, y = bid & 63;
  int tx = threadIdx.x;
  for (int i = tx; i < 576; i += 64) s_w[i] = p1w[i];
  if (tx < 24) { s_b[tx] = p1b[tx]; s_w2[tx] = p2w[tx]; }
  __syncthreads();
  size_t zyx = (size_t)z * 4096 + y * 64 + tx;
  size_t base_b = (size_t)b * CW * NPTS;
  float hreg[24];
  for (int c = 0; c < 24; c++) hreg[c] = h[base_b + (size_t)c * NPTS + zyx];
  float acc = p2b[0];
  for (int o = 0; o < 24; o++) {
    float t = s_b[o];
#pragma unroll
    for (int c = 0; c < 24; c++) t += s_w[o * 24 + c] * hreg[c];
    acc += s_w2[o] * gelu_exact(t);
  }
  out[(size_t)b * NPTS + zyx] = acc;
}

extern "C" void kernel_launch(void* const* d_in, const int* in_sizes, int n_in,
                              void* d_out, int out_size, void* d_ws, size_t ws_size,
                              hipStream_t stream) {
  const float* xin    = (const float*)d_in[0];
  const float* lift_w = (const float*)d_in[1];
  const float* lift_b = (const float*)d_in[2];
  const float* spec_w = (const float*)d_in[3];
  const float* ws_w   = (const float*)d_in[4];
  const float* ws_b   = (const float*)d_in[5];
  const float* loc_w  = (const float*)d_in[6];
  const float* loc_b  = (const float*)d_in[7];
  const float* gn_w   = (const float*)d_in[8];
  const float* gn_b   = (const float*)d_in[9];
  const float* gammas = (const float*)d_in[10];
  const float* p1w    = (const float*)d_in[11];
  const float* p1b    = (const float*)d_in[12];
  const float* p2w    = (const float*)d_in[13];
  const float* p2b    = (const float*)d_in[14];
  float* ws = (float*)d_ws;
  float* out = (float*)d_out;

  // zero GN accumulators (ws is poisoned 0xAA before every launch)
  hipMemsetAsync(ws + OFF_STATS, 0, (NLAYERS * BN * 2 * 2) * sizeof(float), stream);

  k_axis<<<18, 256, 0, stream>>>(lift_w, ws);
  k_lift<<<BN * 4096, 64, 0, stream>>>(xin, lift_w, lift_b, ws);

  for (int l = 0; l < NLAYERS; l++) {
    k_dftx<<<BN * CW * 64, 256, 0, stream>>>(ws + OFF_H, ws + OFF_A1);
    k_dfty<<<BN * CW * 64, 256, 0, stream>>>(ws + OFF_A1, ws + OFF_A2);
    k_dftz<<<BN * CW * 12, 256, 0, stream>>>(ws + OFF_A2, ws + OFF_HF);
    k_mix<<<BN * 27, 256, 0, stream>>>(ws + OFF_HF, spec_w, ws + OFF_OUT, l);
    k_invz<<<BN * CW, 256, 0, stream>>>(ws + OFF_OUT, ws + OFF_A2);      // B1 shares A2
    k_invy<<<BN * CW * 64, 256, 0, stream>>>(ws + OFF_A2, ws + OFF_A1);  // B2 shares A1
    k_layer<<<BN * 4096, 64, 0, stream>>>(ws + OFF_H, ws + OFF_A1, ws_w, ws_b, loc_w, loc_b,
                                          gammas, ws + OFF_PRE, ws + OFF_STATS, l);
    k_gnstat<<<1, 64, 0, stream>>>(ws + OFF_STATS, ws + OFF_NORM, l);
    k_gnapply<<<2048, 256, 0, stream>>>(ws + OFF_PRE, ws + OFF_H, ws + OFF_NORM, gn_w, gn_b, l);
  }
  k_proj<<<BN * 4096, 64, 0, stream>>>(ws + OFF_H, p1w, p1b, p2w, p2b, out);
}